// Round 8
// baseline (802.369 us; speedup 1.0000x reference)
//
#include <hip/hip_runtime.h>
#include <hip/hip_bf16.h>
#include <stdint.h>

// Varlen causal GQA prefill attention, MI355X (gfx950).
// B=4, S=2048, Hq=16, Hkv=4 (G=4), D=128, fp32 I/O, bf16 MFMA internally.
// R8: K double-buffered + V single-buffered (48KB LDS -> 3 blocks/CU target),
// raw s_barrier + lgkmcnt(0) (no vmcnt drain across barriers), tr-read
// pipeline (group 0 hidden under softmax, counted lgkmcnt(8) thereafter),
// setprio(1) around MFMA clusters.
#define NH    16
#define HKVN  4
#define D     128
#define SEQ   2048
#define BATCH 4
#define QTILE 128
#define KVC   64

#define SCALE_LOG2E 0.12751741f   // (1/sqrt(128)) * log2(e), folded into Q
#define THR 11.0f                 // defer-max threshold (log2 units)

typedef __attribute__((ext_vector_type(4)))  float    f32x4;
typedef __attribute__((ext_vector_type(16))) float    f32x16;
typedef __attribute__((ext_vector_type(8)))  short    s16x8;
typedef __attribute__((ext_vector_type(4)))  short    s16x4;
typedef __attribute__((ext_vector_type(4)))  uint32_t u32x4;
typedef __attribute__((ext_vector_type(8)))  __bf16   bf16x8;

__device__ __forceinline__ uint32_t cvt_pk(float lo, float hi) {
  uint32_t r;
  asm("v_cvt_pk_bf16_f32 %0, %1, %2" : "=v"(r) : "v"(lo), "v"(hi));
  return r;
}
// permlane32_swap(a,b): ret0 = {a_low | b_low}, ret1 = {a_high | b_high}.
__device__ __forceinline__ void pswap(uint32_t& a, uint32_t& b) {
  auto r = __builtin_amdgcn_permlane32_swap(a, b, false, false);
  a = r[0];
  b = r[1];
}
__device__ __forceinline__ float cross_max(float x) {
  uint32_t a = __builtin_bit_cast(uint32_t, x), b = a;
  pswap(a, b);
  return fmaxf(__builtin_bit_cast(float, a), __builtin_bit_cast(float, b));
}
__device__ __forceinline__ float cross_sum(float x) {
  uint32_t a = __builtin_bit_cast(uint32_t, x), b = a;
  pswap(a, b);
  return __builtin_bit_cast(float, a) + __builtin_bit_cast(float, b);
}
__device__ __forceinline__ f32x16 mfma32(s16x8 a, s16x8 b, f32x16 c) {
  return __builtin_amdgcn_mfma_f32_32x32x16_bf16(
      __builtin_bit_cast(bf16x8, a), __builtin_bit_cast(bf16x8, b), c, 0, 0, 0);
}

__global__ __launch_bounds__(256, 3) void attn_fwd(
    const float* __restrict__ Q, const float* __restrict__ K,
    const float* __restrict__ V, float* __restrict__ O) {
  // K: [2][64][128] bf16, XOR-swizzled (short idx ^= (row&7)*8). 32KB.
  // V: single [64][128] bf16, subtiled [kv/4][d/16][4][16] for tr_b16. 16KB.
  __shared__ __align__(16) short KT[2][KVC * D];
  __shared__ __align__(16) short VT[KVC * D];

  const int bid = blockIdx.x;
  const int grp = bid >> 8;        // dispatch-order work pairing
  const int i   = bid & 255;
  const int s   = i & 3;
  int qt;
  switch (grp) { case 0: qt = 15 - s; break; case 1: qt = s; break;
                 case 2: qt = 11 - s; break; default: qt = 4 + s; }
  const int bh  = i >> 2;          // 0..63 = b*16 + hq
  const int b   = bh >> 4;
  const int hq  = bh & 15;
  const int hkv = hq >> 2;

  const int tid  = threadIdx.x;
  const int wq   = tid >> 6;
  const int lane = tid & 63;
  const int l31  = lane & 31;
  const int h2   = lane >> 5;
  const int h16  = (lane >> 4) & 1;
  const int l15  = lane & 15;

  const int q0   = qt * QTILE;
  const int qg   = q0 + wq * 32 + l31;
  const int qmin = q0 + wq * 32;
  const int qmax = qmin + 31;
  const int nch  = 2 * qt + 2;

  // ---- Q as B-frags -------------------------------------------------------
  const float* qp = Q + (size_t)(b * SEQ + qg) * (NH * D) + hq * D;
  s16x8 qf[8];
#pragma unroll
  for (int kb = 0; kb < 8; ++kb) {
    f32x4 x0 = *(const f32x4*)(qp + kb * 16 + h2 * 8);
    f32x4 x1 = *(const f32x4*)(qp + kb * 16 + h2 * 8 + 4);
    u32x4 w;
    w[0] = cvt_pk(x0[0] * SCALE_LOG2E, x0[1] * SCALE_LOG2E);
    w[1] = cvt_pk(x0[2] * SCALE_LOG2E, x0[3] * SCALE_LOG2E);
    w[2] = cvt_pk(x1[0] * SCALE_LOG2E, x1[1] * SCALE_LOG2E);
    w[3] = cvt_pk(x1[2] * SCALE_LOG2E, x1[3] * SCALE_LOG2E);
    qf[kb] = __builtin_bit_cast(s16x8, w);
  }

  f32x16 acc[4];
#pragma unroll
  for (int dt = 0; dt < 4; ++dt)
#pragma unroll
    for (int r = 0; r < 16; ++r) acc[dt][r] = 0.f;
  float m_r = -1e30f, l_r = 0.f;

  const float* Kg = K + (size_t)b * SEQ * (HKVN * D) + hkv * D;
  const float* Vg = V + (size_t)b * SEQ * (HKVN * D) + hkv * D;

  const int srow = tid >> 2;        // staging: 4 threads per kv row
  const int scol = (tid & 3) * 32;  // 32 cols each
  const uint32_t vbase = (uint32_t)(uintptr_t)&VT[0];

  f32x4 kl[8], vl[8];
#define STAGE_LOADS(kvb_) do {                                               \
    const float* kr_ = Kg + (size_t)((kvb_) + srow) * (HKVN * D) + scol;     \
    const float* vr_ = Vg + (size_t)((kvb_) + srow) * (HKVN * D) + scol;     \
    _Pragma("unroll") for (int u = 0; u < 8; ++u)                            \
      kl[u] = *(const f32x4*)(kr_ + u * 4);                                  \
    _Pragma("unroll") for (int u = 0; u < 8; ++u)                            \
      vl[u] = *(const f32x4*)(vr_ + u * 4);                                  \
  } while (0)

#define K_WRITE(nbuf_) do {                                                  \
    short* kd_ = &KT[nbuf_][srow * D];                                       \
    _Pragma("unroll") for (int g = 0; g < 4; ++g) {                          \
      u32x4 wk_;                                                             \
      wk_[0] = cvt_pk(kl[2*g][0], kl[2*g][1]);                               \
      wk_[1] = cvt_pk(kl[2*g][2], kl[2*g][3]);                               \
      wk_[2] = cvt_pk(kl[2*g+1][0], kl[2*g+1][1]);                           \
      wk_[3] = cvt_pk(kl[2*g+1][2], kl[2*g+1][3]);                           \
      *(u32x4*)(kd_ + ((scol + g * 8) ^ ((srow & 7) * 8))) = wk_;            \
    }                                                                        \
  } while (0)

#define V_WRITE() do {                                                       \
    _Pragma("unroll") for (int g = 0; g < 4; ++g) {                          \
      u32x4 wv_;                                                             \
      wv_[0] = cvt_pk(vl[2*g][0], vl[2*g][1]);                               \
      wv_[1] = cvt_pk(vl[2*g][2], vl[2*g][3]);                               \
      wv_[2] = cvt_pk(vl[2*g+1][0], vl[2*g+1][1]);                           \
      wv_[3] = cvt_pk(vl[2*g+1][2], vl[2*g+1][3]);                           \
      const int d_ = scol + g * 8;                                           \
      *(u32x4*)(&VT[0] + ((srow >> 2) * 8 + (d_ >> 4)) * 64 +                \
                (srow & 3) * 16 + (d_ & 15)) = wv_;                          \
    }                                                                        \
  } while (0)

// 8 tr reads for output d-tile dt_ into parity slot sl_ (compile-time args)
#define TR_ISSUE(dt_, sl_) do {                                              \
    _Pragma("unroll") for (int ks = 0; ks < 4; ++ks) {                       \
      const uint32_t ad_ = vbase +                                           \
          (uint32_t)((((ks * 4 + h2 * 2) * 8 + 2 * (dt_) + h16) * 64 +       \
                      l15 * 4) * 2);                                         \
      asm volatile("ds_read_b64_tr_b16 %0, %2\n\t"                           \
                   "ds_read_b64_tr_b16 %1, %2 offset:1024"                   \
                   : "=&v"(ta[sl_][ks]), "=&v"(tb[sl_][ks])                  \
                   : "v"(ad_)                                                \
                   : "memory");                                              \
    }                                                                        \
  } while (0)

#define LGKM_BAR() do {                                                      \
    asm volatile("s_waitcnt lgkmcnt(0)" ::: "memory");                       \
    __builtin_amdgcn_s_barrier();                                            \
  } while (0)

  // ---- prologue: chunk 0 staged; chunk-1 loads in flight ------------------
  STAGE_LOADS(0);
  K_WRITE(0);
  V_WRITE();
  if (nch > 1) STAGE_LOADS(KVC);
  LGKM_BAR();

  for (int c = 0; c < nch; ++c) {
    const int cur = c & 1;
    const int kvb = c * KVC;
    const bool have_next = (c + 1 < nch);
    const bool active = (kvb <= qmax);   // wave-uniform

    if (c > 0) {
      V_WRITE();                          // V(c) -> VT (loads from iter c-1)
      if (have_next) {
        STAGE_LOADS(kvb + KVC);           // K,V (c+1); consumed next chunk
        __builtin_amdgcn_sched_barrier(0);
      }
    }

    f32x16 st[2];
    s16x8 pf[4];
    s16x4 ta[2][4], tb[2][4];
    if (active) {
      // ---- S^T = K * Q ---------------------------------------------------
      __builtin_amdgcn_s_setprio(1);
#pragma unroll
      for (int t = 0; t < 2; ++t) {
#pragma unroll
        for (int r = 0; r < 16; ++r) st[t][r] = 0.f;
        const int row = t * 32 + l31;
        const short* rp = &KT[cur][row * D];
        const int sw = (row & 7) * 8;
#pragma unroll
        for (int kb = 0; kb < 8; ++kb) {
          s16x8 kf = *(const s16x8*)(rp + ((kb * 16 + h2 * 8) ^ sw));
          st[t] = mfma32(kf, qf[kb], st[t]);
        }
      }
      __builtin_amdgcn_s_setprio(0);
    }

    LGKM_BAR();   // barrier2: V(c) (and K(c+1) later-irrelevant) visible

    if (active) {
      TR_ISSUE(0, 0);   // V tr reads for dt=0 — latency hidden under softmax

      // ---- causal mask (diagonal chunk only) -----------------------------
      if (kvb + 63 > qmin) {
#pragma unroll
        for (int t = 0; t < 2; ++t)
#pragma unroll
          for (int r = 0; r < 16; ++r) {
            const int kv = kvb + t * 32 + (r & 3) + 8 * (r >> 2) + 4 * h2;
            if (kv > qg) st[t][r] = -1e30f;
          }
      }
      // ---- online softmax, lane-local (q = lane&31) ----------------------
      float pm = st[0][0];
#pragma unroll
      for (int t = 0; t < 2; ++t)
#pragma unroll
        for (int r = 0; r < 16; ++r) pm = fmaxf(pm, st[t][r]);
      const float pmax = cross_max(pm);
      if (__any(pmax > m_r + THR)) {
        const float mn = fmaxf(m_r, pmax);
        const float al = __builtin_amdgcn_exp2f(m_r - mn);
        m_r = mn;
        l_r *= al;
#pragma unroll
        for (int dt = 0; dt < 4; ++dt)
#pragma unroll
          for (int r = 0; r < 16; ++r) acc[dt][r] *= al;
      }
      float p[32];
      float rs = 0.f;
#pragma unroll
      for (int t = 0; t < 2; ++t)
#pragma unroll
        for (int r = 0; r < 16; ++r) {
          const float e = __builtin_amdgcn_exp2f(st[t][r] - m_r);
          p[t * 16 + r] = e;
          rs += e;
        }
      l_r += cross_sum(rs);
      // ---- P -> PV B-frags (T12) -----------------------------------------
#pragma unroll
      for (int ks = 0; ks < 4; ++ks) {
        const int o = (ks >> 1) * 16 + (ks & 1) * 8;
        uint32_t A0 = cvt_pk(p[o + 0], p[o + 1]);
        uint32_t A1 = cvt_pk(p[o + 2], p[o + 3]);
        uint32_t B0 = cvt_pk(p[o + 4], p[o + 5]);
        uint32_t B1 = cvt_pk(p[o + 6], p[o + 7]);
        pswap(A0, B0);  // A0 -> word j01, B0 -> word j45
        pswap(A1, B1);  // A1 -> word j23, B1 -> word j67
        u32x4 w; w[0] = A0; w[1] = A1; w[2] = B0; w[3] = B1;
        pf[ks] = __builtin_bit_cast(s16x8, w);
      }

      // ---- O^T += V^T * P^T, tr reads pipelined 1 group ahead ------------
#pragma unroll
      for (int dt = 0; dt < 4; ++dt) {
        if (dt < 3) {
          TR_ISSUE(dt + 1, (dt + 1) & 1);
          asm volatile("s_waitcnt lgkmcnt(8)" ::: "memory");
        } else {
          asm volatile("s_waitcnt lgkmcnt(0)" ::: "memory");
        }
        __builtin_amdgcn_sched_barrier(0);
        __builtin_amdgcn_s_setprio(1);
#pragma unroll
        for (int ks = 0; ks < 4; ++ks) {
          s16x8 vf = __builtin_shufflevector(ta[dt & 1][ks], tb[dt & 1][ks],
                                             0, 1, 2, 3, 4, 5, 6, 7);
          acc[dt] = mfma32(vf, pf[ks], acc[dt]);
        }
        __builtin_amdgcn_s_setprio(0);
      }
    }

    if (have_next) K_WRITE(cur ^ 1);      // K(c+1) -> KT[nxt]
    LGKM_BAR();   // barrier1: PV reads + K(c+1) writes drained
  }

  // ---- epilogue: O = acc^T / l --------------------------------------------
  const float inv = 1.0f / l_r;
  float* op = O + (size_t)(b * SEQ + qg) * (NH * D) + hq * D;
#pragma unroll
  for (int dt = 0; dt < 4; ++dt) {
#pragma unroll
    for (int rg = 0; rg < 4; ++rg) {
      f32x4 o;
      o[0] = acc[dt][rg * 4 + 0] * inv;
      o[1] = acc[dt][rg * 4 + 1] * inv;
      o[2] = acc[dt][rg * 4 + 2] * inv;
      o[3] = acc[dt][rg * 4 + 3] * inv;
      *(f32x4*)(op + dt * 32 + rg * 8 + h2 * 4) = o;
    }
  }
}

extern "C" void kernel_launch(void* const* d_in, const int* in_sizes, int n_in,
                              void* d_out, int out_size, void* d_ws, size_t ws_size,
                              hipStream_t stream) {
  const float* q = (const float*)d_in[0];
  const float* k = (const float*)d_in[1];
  const float* v = (const float*)d_in[2];
  float* o = (float*)d_out;
  dim3 grid(BATCH * NH * (SEQ / QTILE));  // 1024 blocks
  attn_fwd<<<grid, 256, 0, stream>>>(q, k, v, o);
}